// Round 4
// baseline (450.571 us; speedup 1.0000x reference)
//
#include <hip/hip_runtime.h>

#define B_TOTAL 16384
#define D 128
#define NROWS 27            // 1 dense + 26 sparse
#define BT 16               // batch elements per block
#define DC 32               // D-chunk floats = 128B line per (row,elem)
#define NCHUNK (D / DC)     // 4
#define NSTRIDE 524         // dwords per LDS row: 16*32 + 12 pad (bank spread)
#define OSTRIDE 386         // dwords per element in tri-out staging
#define OUTC 506            // 128 + 378
#define NF4 (NROWS * BT * (DC / 4))   // 3456 float4 per chunk
#define PF_MAX 14           // ceil(3456/256)

__global__ __launch_bounds__(256, 2)
void dotint_kernel(const float* __restrict__ dense,
                   const float* __restrict__ sparse,
                   float* __restrict__ out)
{
    // staging buffer; reused at the end as tri-out buffer (16*386 <= 27*524)
    __shared__ float lds[NROWS * NSTRIDE];

    const int tid = threadIdx.x;
    const int b0  = blockIdx.x * BT;
    const int e   = tid >> 4;        // element 0..15
    const int s   = tid & 15;        // pair-tile 0..15

    // 15 lower-tri tiles of the 5x5 group grid (6-row groups; rows >26 clamp)
    const int sc = (s < 15) ? s : 14;          // s==15 duplicates tile 14, never stored
    const int gi = (sc >= 1) + (sc >= 3) + (sc >= 6) + (sc >= 10);
    const int gj = sc - ((gi * (gi + 1)) >> 1);
    const int i0 = 6 * gi;
    const int j0 = 6 * gj;
    const int eswz = e & 7;

    // precomputed LDS row-base dword offsets (clamped to row 26; clamped rows
    // produce garbage accs that are never stored)
    int rib[6], rjb[6];
    #pragma unroll
    for (int k = 0; k < 6; ++k) {
        int ri_ = i0 + k; if (ri_ > 26) ri_ = 26;
        int rj_ = j0 + k; if (rj_ > 26) rj_ = 26;
        rib[k] = ri_ * NSTRIDE + e * 32;
        rjb[k] = rj_ * NSTRIDE + e * 32;
    }

    // ---- register prefetch pipeline: chunk c+1 loads fly during compute of c
    float4 pf[PF_MAX];

    auto load_chunk = [&](int c) {
        #pragma unroll
        for (int k = 0; k < PF_MAX; ++k) {
            const int f = tid + k * 256;         // float4 id: (row n, elem el, g)
            if (f < NF4) {                        // wave-uniform predicate
                const int n  = f >> 7;
                const int el = (f >> 3) & 15;
                const int g  = f & 7;
                const float* base = (n == 0)
                    ? dense
                    : sparse + (size_t)(n - 1) * ((size_t)B_TOTAL * D);
                pf[k] = *reinterpret_cast<const float4*>(
                    base + (size_t)(b0 + el) * D + c * DC + g * 4);
            }
        }
    };
    auto write_chunk = [&]() {
        #pragma unroll
        for (int k = 0; k < PF_MAX; ++k) {
            const int f = tid + k * 256;
            if (f < NF4) {
                const int n  = f >> 7;
                const int el = (f >> 3) & 15;
                const int g  = f & 7;
                // XOR slot swizzle on the WRITE side; read undoes with q^eswz
                *reinterpret_cast<float4*>(
                    &lds[n * NSTRIDE + el * 32 + ((g ^ (el & 7)) << 2)]) = pf[k];
            }
        }
    };

    float acc[6][6];
    #pragma unroll
    for (int a = 0; a < 6; ++a)
        #pragma unroll
        for (int b = 0; b < 6; ++b) acc[a][b] = 0.f;

    load_chunk(0);   // prologue

    #pragma unroll 1
    for (int c = 0; c < NCHUNK; ++c) {
        __syncthreads();                 // prev compute done reading LDS
        write_chunk();                   // vmcnt wait here is hidden (loads issued 1 chunk ago)
        __syncthreads();                 // writes visible
        if (c < NCHUNK - 1) load_chunk(c + 1);   // issue next chunk's loads NOW

        #pragma unroll
        for (int q = 0; q < 8; ++q) {
            const int s4 = (q ^ eswz) << 2;
            float4 ri[6], rj[6];
            #pragma unroll
            for (int k = 0; k < 6; ++k)
                ri[k] = *reinterpret_cast<const float4*>(&lds[rib[k] + s4]);
            #pragma unroll
            for (int k = 0; k < 6; ++k)
                rj[k] = *reinterpret_cast<const float4*>(&lds[rjb[k] + s4]);
            #pragma unroll
            for (int a = 0; a < 6; ++a)
                #pragma unroll
                for (int b = 0; b < 6; ++b) {
                    acc[a][b] = fmaf(ri[a].x, rj[b].x, acc[a][b]);
                    acc[a][b] = fmaf(ri[a].y, rj[b].y, acc[a][b]);
                    acc[a][b] = fmaf(ri[a].z, rj[b].z, acc[a][b]);
                    acc[a][b] = fmaf(ri[a].w, rj[b].w, acc[a][b]);
                }
        }
    }

    // ---- tri results -> LDS (scattered dwords, cheap), then coalesced write
    __syncthreads();
    if (s < 15) {
        #pragma unroll
        for (int a = 0; a < 6; ++a) {
            const int i = i0 + a;
            if (i < NROWS) {
                const int ibase = (i * (i + 1)) >> 1;
                #pragma unroll
                for (int b = 0; b < 6; ++b) {
                    const int j = j0 + b;
                    if (j < NROWS && j <= i)
                        lds[e * OSTRIDE + ibase + j] = acc[a][b];
                }
            }
        }
    }
    __syncthreads();

    // block's output region: 16 rows x 506 f32 = 4048 float2, contiguous
    float* oblk = out + (size_t)b0 * OUTC;
    #pragma unroll
    for (int k = 0; k < 16; ++k) {
        const int f2 = tid + k * 256;          // float2 index 0..4047
        if (f2 < 8 * OUTC) {
            const int b = f2 / 253;            // elem (const-div -> magic mul)
            const int cc = 2 * f2 - b * OUTC;  // 0..504 even; never straddles boundary
            float2 v;
            if (cc < D) {
                v = *reinterpret_cast<const float2*>(dense + (size_t)(b0 + b) * D + cc);
            } else {
                v = *reinterpret_cast<const float2*>(&lds[b * OSTRIDE + (cc - D)]);
            }
            *reinterpret_cast<float2*>(oblk + (size_t)b * OUTC + cc) = v;
        }
    }
}

extern "C" void kernel_launch(void* const* d_in, const int* in_sizes, int n_in,
                              void* d_out, int out_size, void* d_ws, size_t ws_size,
                              hipStream_t stream)
{
    const float* dense  = (const float*)d_in[0];
    const float* sparse = (const float*)d_in[1];
    float* out          = (float*)d_out;

    dim3 grid(B_TOTAL / BT);   // 1024 blocks, 2 resident/CU (LDS-limited)
    dim3 block(256);
    hipLaunchKernelGGL(dotint_kernel, grid, block, 0, stream, dense, sparse, out);
}

// Round 5
// 347.221 us; speedup vs baseline: 1.2976x; 1.2976x over previous
//
#include <hip/hip_runtime.h>

#define B_TOTAL 16384
#define D 128
#define NROWS 27             // 1 dense + 26 sparse
#define BT 8                 // batch elements per block
#define DC 32                // 128B per (row, element) per chunk
#define NCHUNK (D / DC)      // 4
#define RS 260               // dwords per LDS row: 8 el * 32 f32 + 4 pad (stride ≡4 mod 32)
#define BUFSZ (NROWS * RS)   // 7020 dw per buffer
#define OSTRIDE 386          // dwords per element in tri-out staging
#define OUTC 506             // 128 + 378

__global__ __launch_bounds__(128, 1)
void dotint_kernel(const float* __restrict__ dense,
                   const float* __restrict__ sparse,
                   float* __restrict__ out)
{
    __shared__ float lds[2 * BUFSZ];   // 56,160 B -> 2 blocks/CU

    const int tid = threadIdx.x;
    const int b0  = blockIdx.x * BT;
    const int e   = tid >> 4;          // element 0..7
    const int s   = tid & 15;          // pair-tile 0..15

    // 15 lower-tri 6x6 tiles of the 5x5 group grid (rows >26 clamp on read)
    const int sc = (s < 15) ? s : 14;  // s==15 duplicates tile 14, never stored
    const int gi = (sc >= 1) + (sc >= 3) + (sc >= 6) + (sc >= 10);
    const int gj = sc - ((gi * (gi + 1)) >> 1);
    const int i0 = 6 * gi;
    const int j0 = 6 * gj;

    // LDS row-base dword offsets (clamped rows produce garbage, never stored)
    int rib[6], rjb[6];
    #pragma unroll
    for (int k = 0; k < 6; ++k) {
        int ri_ = i0 + k; if (ri_ > 26) ri_ = 26;
        int rj_ = j0 + k; if (rj_ > 26) rj_ = 26;
        rib[k] = ri_ * RS + e * 32;
        rjb[k] = rj_ * RS + e * 32;
    }

    // staging decode: one instr = one row (8 el x 128B = 1KB), lanes linear in LDS
    const int wave = tid >> 6;         // 0..1
    const int lane = tid & 63;
    const int el   = lane >> 3;        // element 0..7
    const int sq   = lane & 7;         // 16B slot; XOR swizzle applied on global src

    auto stage = [&](int c, int buf) {
        for (int n = wave; n < NROWS; n += 2) {   // wave0: 14 rows, wave1: 13
            const float* base = (n == 0)
                ? dense
                : sparse + (size_t)(n - 1) * ((size_t)B_TOTAL * D);
            const float* src = base + (size_t)(b0 + el) * D + c * DC + ((sq ^ el) << 2);
            __builtin_amdgcn_global_load_lds(
                (const __attribute__((address_space(1))) void*)src,
                (__attribute__((address_space(3))) void*)&lds[buf * BUFSZ + n * RS],
                16, 0, 0);
        }
    };

    float acc[6][6];
    #pragma unroll
    for (int a = 0; a < 6; ++a)
        #pragma unroll
        for (int b = 0; b < 6; ++b) acc[a][b] = 0.f;

    stage(0, 0);   // prologue

    #pragma unroll 1
    for (int c = 0; c < NCHUNK; ++c) {
        if (c > 0) {
            // all waves done READING buf[(c+1)&1] (chunk c-1) before overwrite
            asm volatile("" ::: "memory");
            __builtin_amdgcn_s_barrier();
            asm volatile("" ::: "memory");
        }
        if (c + 1 < NCHUNK) {
            stage(c + 1, (c + 1) & 1);
            // counted wait: drains chunk c's loads, leaves chunk c+1's in flight
            asm volatile("s_waitcnt vmcnt(13)" ::: "memory");
        } else {
            asm volatile("s_waitcnt vmcnt(0)" ::: "memory");
        }
        __builtin_amdgcn_sched_barrier(0);
        __builtin_amdgcn_s_barrier();      // raw barrier: NO auto vmcnt(0) drain
        asm volatile("" ::: "memory");

        const float* bp = &lds[(c & 1) * BUFSZ];
        #pragma unroll
        for (int q = 0; q < 8; ++q) {
            const int s4 = (q ^ e) << 2;   // undo source-side slot swizzle
            float4 ri[6], rj[6];
            #pragma unroll
            for (int k = 0; k < 6; ++k)
                ri[k] = *reinterpret_cast<const float4*>(&bp[rib[k] + s4]);
            #pragma unroll
            for (int k = 0; k < 6; ++k)
                rj[k] = *reinterpret_cast<const float4*>(&bp[rjb[k] + s4]);
            #pragma unroll
            for (int a = 0; a < 6; ++a)
                #pragma unroll
                for (int b = 0; b < 6; ++b) {
                    acc[a][b] = fmaf(ri[a].x, rj[b].x, acc[a][b]);
                    acc[a][b] = fmaf(ri[a].y, rj[b].y, acc[a][b]);
                    acc[a][b] = fmaf(ri[a].z, rj[b].z, acc[a][b]);
                    acc[a][b] = fmaf(ri[a].w, rj[b].w, acc[a][b]);
                }
        }
    }

    // ---- tri results -> LDS (scattered dwords), then coalesced global write
    __syncthreads();
    if (s < 15) {
        #pragma unroll
        for (int a = 0; a < 6; ++a) {
            const int i = i0 + a;
            if (i < NROWS) {
                const int ibase = (i * (i + 1)) >> 1;
                #pragma unroll
                for (int b = 0; b < 6; ++b) {
                    const int j = j0 + b;
                    if (j < NROWS && j <= i)
                        lds[e * OSTRIDE + ibase + j] = acc[a][b];
                }
            }
        }
    }
    __syncthreads();

    // block's output region: 8 rows x 506 f32 = 2024 float2, contiguous
    float* oblk = out + (size_t)b0 * OUTC;
    #pragma unroll
    for (int k = 0; k < 16; ++k) {
        const int f2 = tid + k * 128;          // float2 index 0..2023
        if (f2 < 4 * OUTC) {
            const int b = f2 / 253;            // element 0..7 (const-div -> magic mul)
            const int cc = 2 * f2 - b * OUTC;  // 0..504 even; never straddles boundary
            float2 v;
            if (cc < D) {
                v = *reinterpret_cast<const float2*>(dense + (size_t)(b0 + b) * D + cc);
            } else {
                v = *reinterpret_cast<const float2*>(&lds[b * OSTRIDE + (cc - D)]);
            }
            *reinterpret_cast<float2*>(oblk + (size_t)b * OUTC + cc) = v;
        }
    }
}

extern "C" void kernel_launch(void* const* d_in, const int* in_sizes, int n_in,
                              void* d_out, int out_size, void* d_ws, size_t ws_size,
                              hipStream_t stream)
{
    const float* dense  = (const float*)d_in[0];
    const float* sparse = (const float*)d_in[1];
    float* out          = (float*)d_out;

    dim3 grid(B_TOTAL / BT);   // 2048 blocks, 2 resident/CU (LDS-limited)
    dim3 block(128);
    hipLaunchKernelGGL(dotint_kernel, grid, block, 0, stream, dense, sparse, out);
}